// Round 1
// baseline (228.494 us; speedup 1.0000x reference)
//
#include <hip/hip_runtime.h>

// CIN (xDeepFM) fused kernel for MI355X.
// B=4096, F=32, D=32, layers: M1=32 (K1=1024), M2=128 (K2=4096), N=128.
// Strategy: per layer, GEMM over rows=(b,d) with A generated in registers:
//   A[(b,d)][h*M+m] = x0[b,h,d] * prev[b,m,d]
// K-loop order (m_chunk outer, h inner) lets the P-fragment (prev slice) be
// reused across 32 h-steps; A-frag = splat(x[h,d]) * P via v_pk_mul_f16.

typedef _Float16 half_t;
typedef _Float16 half8 __attribute__((ext_vector_type(8)));
typedef float f32x4 __attribute__((ext_vector_type(4)));

// ---------------- W pre-pack: fp32 [K][128] -> f16 Wp[kidx][n][t] ----------
// kidx = mc*32 + h, t = quad*8+j, original k = h*M + mc*32 + t.
template <int M>
__global__ void prep_w_kernel(const float* __restrict__ W,
                              half_t* __restrict__ Wp) {
  int gid = blockIdx.x * 256 + threadIdx.x;
  int t = gid & 31;
  int n = (gid >> 5) & 127;
  int kidx = gid >> 12;
  int h = kidx & 31;
  int mc = kidx >> 5;
  int k = h * M + mc * 32 + t;
  Wp[gid] = (half_t)W[k * 128 + n];
}

// ---------------- fused CIN layer ------------------------------------------
// Block: 4 b's = 128 rows x 128 cols. 4 waves in 2x2 (row-half x col-half).
// Wave: 4 row-tiles x 4 col-tiles of 16x16 (mfma_f32_16x16x32_f16).
template <int M, int PSTR, bool IS_L1>
__global__ __launch_bounds__(256, 4) void cin_layer_kernel(
    const float* __restrict__ x0,      // [B][32][32] fp32
    const half_t* __restrict__ prevG,  // layer2: cur1T [B][32][128] f16
    const half_t* __restrict__ Wp,     // packed filter
    half_t* __restrict__ curT,         // layer1 out: cur1T [B][32][128] f16
    float* __restrict__ out,           // [B][256] fp32
    int outColBase) {
  __shared__ half_t xsf[4 * 32 * 32];        // x f16, [bi][h][d]
  __shared__ half_t prevT[4 * 32 * PSTR];    // prev transposed, [bi][d][m]

  const int tid = threadIdx.x;
  const int b0 = blockIdx.x * 4;

  // ---- stage x0 (and prevT for layer 1) ----
  const float4* x4 = (const float4*)(x0 + (size_t)b0 * 1024);
#pragma unroll
  for (int r = 0; r < 4; ++r) {
    int q = r * 256 + tid;          // float4 index within 4096-float region
    float4 v = x4[q];
    int e = q * 4;
    int bi = e >> 10, h = (e >> 5) & 31, d0 = e & 31;
    half_t h0 = (half_t)v.x, h1 = (half_t)v.y, h2 = (half_t)v.z,
           h3 = (half_t)v.w;
    half_t* xp = &xsf[(bi * 32 + h) * 32 + d0];
    xp[0] = h0; xp[1] = h1; xp[2] = h2; xp[3] = h3;
    if (IS_L1) {
      prevT[(bi * 32 + d0 + 0) * PSTR + h] = h0;
      prevT[(bi * 32 + d0 + 1) * PSTR + h] = h1;
      prevT[(bi * 32 + d0 + 2) * PSTR + h] = h2;
      prevT[(bi * 32 + d0 + 3) * PSTR + h] = h3;
    }
  }
  if (!IS_L1) {
    // stage cur1T f16 [4][32][128] -> prevT (straight copy, PSTR==128)
    const uint4* c4 = (const uint4*)(prevG + (size_t)b0 * 32 * 128);
#pragma unroll
    for (int r = 0; r < 8; ++r) {
      int q = r * 256 + tid;        // 8-half chunk index
      uint4 v = c4[q];
      int e = q * 8;
      int bi = e >> 12, d = (e >> 7) & 31, m0 = e & 127;
      *(uint4*)&prevT[(bi * 32 + d) * PSTR + m0] = v;
    }
  }
  __syncthreads();

  const int lane = tid & 63;
  const int l15 = lane & 15;
  const int quad = lane >> 4;
  const int wave = tid >> 6;
  const int wr = wave >> 1;   // row half: b's {2wr, 2wr+1}
  const int wc = wave & 1;    // col half: n in [64wc, 64wc+64)

  f32x4 acc[4][4];
#pragma unroll
  for (int i = 0; i < 4; ++i)
#pragma unroll
    for (int j = 0; j < 4; ++j) acc[i][j] = (f32x4){0.f, 0.f, 0.f, 0.f};

  int woff[4];  // per-lane W offsets (halfs), invariant over k-steps
#pragma unroll
  for (int ct = 0; ct < 4; ++ct)
    woff[ct] = ((wc * 64 + ct * 16 + l15) << 5) + (quad << 3);

  constexpr int MC = M / 32;
#pragma unroll 1
  for (int mc = 0; mc < MC; ++mc) {
    half8 P[4];  // P-frag per row-tile: prev[m_chunk slice, d] — reused 32x
#pragma unroll
    for (int rt = 0; rt < 4; ++rt) {
      int bi = wr * 2 + (rt >> 1);
      int d = (rt & 1) * 16 + l15;
      P[rt] = *(const half8*)&prevT[(bi * 32 + d) * PSTR + mc * 32 + quad * 8];
    }
#pragma unroll 2
    for (int h = 0; h < 32; ++h) {
      const half_t* wrow = Wp + (size_t)(mc * 32 + h) * 4096;
      half8 Bf[4];
#pragma unroll
      for (int ct = 0; ct < 4; ++ct)
        Bf[ct] = *(const half8*)(wrow + woff[ct]);
#pragma unroll
      for (int rt = 0; rt < 4; ++rt) {
        int bi = wr * 2 + (rt >> 1);
        int d = (rt & 1) * 16 + l15;
        half_t x = xsf[(bi * 32 + h) * 32 + d];   // broadcast read
        half8 Af = P[rt] * x;                     // 4x v_pk_mul_f16
#pragma unroll
        for (int ct = 0; ct < 4; ++ct)
          acc[rt][ct] = __builtin_amdgcn_mfma_f32_16x16x32_f16(
              Af, Bf[ct], acc[rt][ct], 0, 0, 0);
      }
    }
  }

  // ---- epilogue: relu, store cur1T (layer1), d-sum -> out ----
#pragma unroll
  for (int bil = 0; bil < 2; ++bil) {
    const int bi = wr * 2 + bil;
#pragma unroll
    for (int ct = 0; ct < 4; ++ct) {
      float s = 0.f;
#pragma unroll
      for (int dh = 0; dh < 2; ++dh) {
        const int rt = bil * 2 + dh;
        f32x4 a = acc[rt][ct];
#pragma unroll
        for (int r = 0; r < 4; ++r) {
          float v = a[r] > 0.f ? a[r] : 0.f;
          s += v;
          if (IS_L1) {
            int drow = dh * 16 + quad * 4 + r;  // C/D: row = quad*4+reg
            curT[((size_t)(b0 + bi) * 32 + drow) * 128 + wc * 64 + ct * 16 +
                 l15] = (half_t)v;
          }
        }
      }
      s += __shfl_down(s, 32);  // quad0+=quad2, quad1+=quad3
      s += __shfl_down(s, 16);  // quad0+=quad1
      if (lane < 16)
        out[(size_t)(b0 + bi) * 256 + outColBase + wc * 64 + ct * 16 + lane] =
            s;
    }
  }
}

extern "C" void kernel_launch(void* const* d_in, const int* in_sizes, int n_in,
                              void* d_out, int out_size, void* d_ws,
                              size_t ws_size, hipStream_t stream) {
  const float* x0 = (const float*)d_in[0];   // [4096,32,32]
  const float* w0 = (const float*)d_in[1];   // [1,1024,128]
  const float* w1 = (const float*)d_in[2];   // [1,4096,128]
  float* out = (float*)d_out;                // [4096,256]
  char* ws = (char*)d_ws;

  half_t* Wp0 = (half_t*)(ws);                                   // 256 KB
  half_t* Wp1 = (half_t*)(ws + 1024 * 128 * 2);                  // 1 MB
  half_t* c1T = (half_t*)(ws + 1024 * 128 * 2 + 4096 * 128 * 2); // 32 MB

  hipLaunchKernelGGL((prep_w_kernel<32>), dim3(512), dim3(256), 0, stream, w0,
                     Wp0);
  hipLaunchKernelGGL((prep_w_kernel<128>), dim3(2048), dim3(256), 0, stream,
                     w1, Wp1);
  hipLaunchKernelGGL((cin_layer_kernel<32, 40, true>), dim3(1024), dim3(256),
                     0, stream, x0, (const half_t*)nullptr, Wp0, c1T, out, 0);
  hipLaunchKernelGGL((cin_layer_kernel<128, 128, false>), dim3(1024),
                     dim3(256), 0, stream, x0, c1T, Wp1, (half_t*)nullptr, out,
                     128);
}

// Round 2
// 217.004 us; speedup vs baseline: 1.0529x; 1.0529x over previous
//
#include <hip/hip_runtime.h>

// CIN (xDeepFM) fully-fused kernel for MI355X.
// B=4096, F=32, D=32; layer1: K1=1024 -> N=128; layer2: K2=4096 -> N=128.
// GEMM rows = (b,d), A generated in registers: A[(b,d)][h*M+m] = x0[b,h,d]*prev[b,m,d].
// mfma_f32_32x32x16_f16: wave = 4 b's (128 rows) x 32 cols; 1 B-load feeds 4 MFMAs.
// Both layers fused: cur1 lives only in LDS (relu'd f16, [bi][d][m]).

typedef _Float16 half_t;
typedef _Float16 half4v __attribute__((ext_vector_type(4)));
typedef _Float16 half8 __attribute__((ext_vector_type(8)));
typedef float f32x16 __attribute__((ext_vector_type(16)));

// ---- W pack: fp32 [K][128] -> f16 Wp[s][tg][n][8],  s = mc*32+h, t = tg*8+j,
//      original k = h*M + mc*16 + t.  Reads coalesced (n fastest).
template <int M>
__global__ void prep_w_kernel(const float* __restrict__ W,
                              half_t* __restrict__ Wp) {
  int gid = blockIdx.x * 256 + threadIdx.x;
  int n = gid & 127;
  int r = gid >> 7;
  int t = r & 15;
  int s = r >> 4;
  int h = s & 31;
  int mc = s >> 5;
  int k = h * M + mc * 16 + t;
  Wp[(((s * 2 + (t >> 3)) * 128 + n) << 3) + (t & 7)] = (half_t)W[k * 128 + n];
}

__global__ __launch_bounds__(256, 4) void cin_fused_kernel(
    const float* __restrict__ x0,      // [4096][32][32] fp32
    const half_t* __restrict__ Wp0,    // packed, 64*2048 halfs
    const half_t* __restrict__ Wp1,    // packed, 256*2048 halfs
    float* __restrict__ out) {         // [4096][256]
  __shared__ half_t xsf[4 * 32 * 32];     // [bi][h][d] f16
  __shared__ half_t prevT[4 * 32 * 128];  // phase2: [bi][d][m]; phase1 alias: xT stride 40
  half_t* xT = prevT;                     // [bi*32+d][h], stride 40 (16B-aligned rows)

  const int tid = threadIdx.x;
  const int b0 = blockIdx.x * 4;

  // ---- stage x0 -> xsf ([h][d]) and xT ([d][h], for layer-1 A-gen) ----
  const float4* x4 = (const float4*)(x0 + (size_t)b0 * 1024);
#pragma unroll
  for (int r = 0; r < 4; ++r) {
    int q = r * 256 + tid;
    float4 v = x4[q];
    int e = q * 4;
    int bi = e >> 10, h = (e >> 5) & 31, d0 = e & 31;
    half4v hv = {(half_t)v.x, (half_t)v.y, (half_t)v.z, (half_t)v.w};
    *(half4v*)&xsf[(bi * 32 + h) * 32 + d0] = hv;
    xT[(bi * 32 + d0 + 0) * 40 + h] = hv[0];
    xT[(bi * 32 + d0 + 1) * 40 + h] = hv[1];
    xT[(bi * 32 + d0 + 2) * 40 + h] = hv[2];
    xT[(bi * 32 + d0 + 3) * 40 + h] = hv[3];
  }
  __syncthreads();

  const int lane = tid & 63;
  const int l31 = lane & 31;
  const int hi = lane >> 5;      // k half: k = hi*8 + j
  const int wave = tid >> 6;
  const int n0 = wave * 32;      // this wave's 32 output cols

  const f32x16 z16 = {0.f, 0.f, 0.f, 0.f, 0.f, 0.f, 0.f, 0.f,
                      0.f, 0.f, 0.f, 0.f, 0.f, 0.f, 0.f, 0.f};
  f32x16 acc[4];
#pragma unroll
  for (int rt = 0; rt < 4; ++rt) acc[rt] = z16;

  // per-lane W pointer: element [s][hi][n0+l31][0]
  const half_t* wp0 = Wp0 + (size_t)hi * 1024 + (size_t)(n0 + l31) * 8;
  const half_t* wp1 = Wp1 + (size_t)hi * 1024 + (size_t)(n0 + l31) * 8;

  // ================= layer 1 (K=1024: 2 m-chunks x 32 h) =================
#pragma unroll 1
  for (int mc = 0; mc < 2; ++mc) {
    half8 P[4];
#pragma unroll
    for (int rt = 0; rt < 4; ++rt)
      P[rt] = *(const half8*)&xT[(rt * 32 + l31) * 40 + mc * 16 + hi * 8];
    const half_t* wrow = wp0 + (size_t)mc * 32 * 2048;
#pragma unroll 2
    for (int h = 0; h < 32; ++h) {
      half8 Bf = *(const half8*)(wrow + (size_t)h * 2048);
#pragma unroll
      for (int rt = 0; rt < 4; ++rt) {
        half_t xv = xsf[(rt * 32 + h) * 32 + l31];
        half8 Af = P[rt] * xv;
        acc[rt] = __builtin_amdgcn_mfma_f32_32x32x16_f16(Af, Bf, acc[rt], 0, 0, 0);
      }
    }
  }

  __syncthreads();  // all waves done reading xT before prevT overwrite

  // ---- epilogue 1: relu, cur1 -> prevT [bi][d][m], d-sum -> out[:, 0:128] ----
#pragma unroll
  for (int rt = 0; rt < 4; ++rt) {
    float s = 0.f;
#pragma unroll
    for (int r = 0; r < 16; ++r) {
      float v = acc[rt][r];
      v = v > 0.f ? v : 0.f;
      s += v;
      int d = (r & 3) + ((r >> 2) * 8) + hi * 4;  // C/D row map (32x32)
      prevT[(rt * 32 + d) * 128 + n0 + l31] = (half_t)v;
    }
    s += __shfl_down(s, 32);
    if (lane < 32) out[(size_t)(b0 + rt) * 256 + n0 + lane] = s;
    acc[rt] = z16;
  }
  __syncthreads();

  // ================= layer 2 (K=4096: 8 m-chunks x 32 h) =================
#pragma unroll 1
  for (int mc = 0; mc < 8; ++mc) {
    half8 P[4];
#pragma unroll
    for (int rt = 0; rt < 4; ++rt)
      P[rt] = *(const half8*)&prevT[(rt * 32 + l31) * 128 + mc * 16 + hi * 8];
    const half_t* wrow = wp1 + (size_t)mc * 32 * 2048;
#pragma unroll 2
    for (int h = 0; h < 32; ++h) {
      half8 Bf = *(const half8*)(wrow + (size_t)h * 2048);
#pragma unroll
      for (int rt = 0; rt < 4; ++rt) {
        half_t xv = xsf[(rt * 32 + h) * 32 + l31];
        half8 Af = P[rt] * xv;
        acc[rt] = __builtin_amdgcn_mfma_f32_32x32x16_f16(Af, Bf, acc[rt], 0, 0, 0);
      }
    }
  }

  // ---- epilogue 2: relu, d-sum -> out[:, 128:256] ----
#pragma unroll
  for (int rt = 0; rt < 4; ++rt) {
    float s = 0.f;
#pragma unroll
    for (int r = 0; r < 16; ++r) {
      float v = acc[rt][r];
      s += v > 0.f ? v : 0.f;
    }
    s += __shfl_down(s, 32);
    if (lane < 32)
      out[(size_t)(b0 + rt) * 256 + 128 + n0 + lane] = s;
  }
}

extern "C" void kernel_launch(void* const* d_in, const int* in_sizes, int n_in,
                              void* d_out, int out_size, void* d_ws,
                              size_t ws_size, hipStream_t stream) {
  const float* x0 = (const float*)d_in[0];  // [4096,32,32]
  const float* w0 = (const float*)d_in[1];  // [1,1024,128]
  const float* w1 = (const float*)d_in[2];  // [1,4096,128]
  float* out = (float*)d_out;               // [4096,256]
  char* ws = (char*)d_ws;

  half_t* Wp0 = (half_t*)(ws);                   // 64*2048 f16 = 256 KB
  half_t* Wp1 = (half_t*)(ws + 64 * 2048 * 2);   // 256*2048 f16 = 1 MB

  hipLaunchKernelGGL((prep_w_kernel<32>), dim3(512), dim3(256), 0, stream, w0,
                     Wp0);
  hipLaunchKernelGGL((prep_w_kernel<128>), dim3(2048), dim3(256), 0, stream,
                     w1, Wp1);
  hipLaunchKernelGGL(cin_fused_kernel, dim3(1024), dim3(256), 0, stream, x0,
                     Wp0, Wp1, out);
}

// Round 3
// 215.281 us; speedup vs baseline: 1.0614x; 1.0080x over previous
//
#include <hip/hip_runtime.h>

// CIN (xDeepFM) fully-fused kernel for MI355X.
// B=4096, F=32, D=32; layer1: K1=1024 -> N=128; layer2: K2=4096 -> N=128.
// GEMM rows=(b,d); A generated in registers: A[(b,d)][h*M+m] = x0[b,h,d]*prev[b,m,d].
// mfma_f32_32x32x16_f16: wave = 4 b's (128 rows) x 32 cols.
// R3: prevT XOR-swizzle (bank spread), x via single ds_read_b64 ([h][d][bi] layout),
//     depth-2 register prefetch pipeline on B-frags, scalar-base B addressing.

typedef _Float16 half_t;
typedef _Float16 half4v __attribute__((ext_vector_type(4)));
typedef _Float16 half8 __attribute__((ext_vector_type(8)));
typedef float f32x16 __attribute__((ext_vector_type(16)));

// ---- W pack (both filters, one launch): thread=(s,tg,n): 8 coalesced float
// loads (fixed k per lane-row), one 16B store. Wp[s][tg][n][8], k=h*M+mc*16+tg*8+j.
__global__ void prep_w_kernel(const float* __restrict__ W0,
                              const float* __restrict__ W1,
                              half_t* __restrict__ Wp0,
                              half_t* __restrict__ Wp1) {
  int gid = blockIdx.x * 256 + threadIdx.x;  // 320*256 threads
  int n = gid & 127;
  int tg = (gid >> 7) & 1;
  int s = gid >> 8;  // 0..319
  const float* W;
  half_t* Wp;
  int M, sl;
  if (s < 64) { W = W0; Wp = Wp0; M = 32; sl = s; }
  else        { W = W1; Wp = Wp1; M = 128; sl = s - 64; }
  int h = sl & 31, mc = sl >> 5;
  int kbase = h * M + mc * 16 + tg * 8;
  half8 v;
#pragma unroll
  for (int j = 0; j < 8; ++j) v[j] = (half_t)W[(size_t)(kbase + j) * 128 + n];
  *(half8*)(Wp + ((size_t)(sl * 2 + tg) * 128 + n) * 8) = v;
}

// swizzled prevT index: logical (row, m) -> halfs offset. 16B chunk XOR spread.
__device__ __forceinline__ int pswz(int row, int m) {
  return row * 128 + ((((m) >> 3) ^ (row & 15)) << 3) + (m & 7);
}

__global__ __launch_bounds__(256, 4) void cin_fused_kernel(
    const float* __restrict__ x0,    // [4096][32][32] fp32
    const half_t* __restrict__ Wp0,  // 64*2048 halfs
    const half_t* __restrict__ Wp1,  // 256*2048 halfs
    float* __restrict__ out) {       // [4096][256]
  __shared__ half_t xsf2[32 * 32 * 4];    // [h][d][bi] f16 (8 KB)
  __shared__ half_t prevT[4 * 32 * 128];  // swizzled [bi][d][m] (32 KB); L1 alias xT
  half_t* xT = prevT;                     // [bi*32+d][h], stride 40 halfs

  const int tid = threadIdx.x;
  const int b0 = blockIdx.x * 4;

  // ---- stage x0 -> xsf2 ([h][d][bi]) and xT ([d][h]) ----
  const float4* x4 = (const float4*)(x0 + (size_t)b0 * 1024);
#pragma unroll
  for (int r = 0; r < 4; ++r) {
    int q = r * 256 + tid;
    float4 v = x4[q];
    int e = q * 4;
    int bi = e >> 10, h = (e >> 5) & 31, d0 = e & 31;
    half4v hv = {(half_t)v.x, (half_t)v.y, (half_t)v.z, (half_t)v.w};
#pragma unroll
    for (int j = 0; j < 4; ++j) {
      xsf2[(h * 32 + d0 + j) * 4 + bi] = hv[j];
      xT[(bi * 32 + d0 + j) * 40 + h] = hv[j];
    }
  }
  __syncthreads();

  const int lane = tid & 63;
  const int l31 = lane & 31;
  const int hi = lane >> 5;
  const int wave = tid >> 6;
  const int n0 = wave * 32;

  f32x16 acc[4];
#pragma unroll
  for (int rt = 0; rt < 4; ++rt)
#pragma unroll
    for (int r = 0; r < 16; ++r) acc[rt][r] = 0.f;

  const int woff = hi * 1024 + (n0 + l31) * 8;  // per-lane B offset (halfs)
  const half_t* xrd = &xsf2[l31 * 4];           // + h*128 halfs

  half8 P[4];
  half8 Bc0, Bc1;

  // ================= layer 1 (s = 0..63, mc = s>>5, h = s&31) =================
  Bc0 = *(const half8*)(Wp0 + 0 * 2048 + woff);
  Bc1 = *(const half8*)(Wp0 + 1 * 2048 + woff);
#pragma unroll 1
  for (int mc = 0; mc < 2; ++mc) {
#pragma unroll
    for (int rt = 0; rt < 4; ++rt)
      P[rt] = *(const half8*)&xT[(rt * 32 + l31) * 40 + mc * 16 + hi * 8];
#pragma unroll 1
    for (int gg = 0; gg < 16; ++gg) {
      int s2 = mc * 32 + gg * 2;
      int sn = (s2 + 2) & 63;
      half8 Bn0 = *(const half8*)(Wp0 + (size_t)sn * 2048 + woff);
      half8 Bn1 = *(const half8*)(Wp0 + (size_t)(sn + 1) * 2048 + woff);
#pragma unroll
      for (int j = 0; j < 2; ++j) {
        int h = gg * 2 + j;
        half4v xq = *(const half4v*)(xrd + h * 128);
        half8 B = j ? Bc1 : Bc0;
#pragma unroll
        for (int rt = 0; rt < 4; ++rt) {
          half8 Af = P[rt] * xq[rt];
          acc[rt] =
              __builtin_amdgcn_mfma_f32_32x32x16_f16(Af, B, acc[rt], 0, 0, 0);
        }
      }
      Bc0 = Bn0;
      Bc1 = Bn1;
    }
  }

  __syncthreads();  // all waves done reading xT before prevT overwrite

  // ---- epilogue 1: relu, cur1 -> prevT (swizzled), d-sum -> out[:, 0:128] ----
#pragma unroll
  for (int rt = 0; rt < 4; ++rt) {
    float s = 0.f;
#pragma unroll
    for (int r = 0; r < 16; ++r) {
      float v = acc[rt][r];
      v = v > 0.f ? v : 0.f;
      s += v;
      int d = (r & 3) + ((r >> 2) << 3) + hi * 4;  // C/D row map (32x32)
      prevT[pswz(rt * 32 + d, n0 + l31)] = (half_t)v;
      acc[rt][r] = 0.f;
    }
    s += __shfl_down(s, 32);
    if (lane < 32) out[(size_t)(b0 + rt) * 256 + n0 + lane] = s;
  }
  __syncthreads();

  // ================= layer 2 (s = 0..255, mc = s>>5, h = s&31) ================
  Bc0 = *(const half8*)(Wp1 + 0 * 2048 + woff);
  Bc1 = *(const half8*)(Wp1 + 1 * 2048 + woff);
#pragma unroll 1
  for (int mc = 0; mc < 8; ++mc) {
#pragma unroll
    for (int rt = 0; rt < 4; ++rt)
      P[rt] = *(const half8*)&prevT[pswz(rt * 32 + l31, mc * 16 + hi * 8)];
#pragma unroll 1
    for (int gg = 0; gg < 16; ++gg) {
      int s2 = mc * 32 + gg * 2;
      int sn = (s2 + 2) & 255;
      half8 Bn0 = *(const half8*)(Wp1 + (size_t)sn * 2048 + woff);
      half8 Bn1 = *(const half8*)(Wp1 + (size_t)(sn + 1) * 2048 + woff);
#pragma unroll
      for (int j = 0; j < 2; ++j) {
        int h = gg * 2 + j;
        half4v xq = *(const half4v*)(xrd + h * 128);
        half8 B = j ? Bc1 : Bc0;
#pragma unroll
        for (int rt = 0; rt < 4; ++rt) {
          half8 Af = P[rt] * xq[rt];
          acc[rt] =
              __builtin_amdgcn_mfma_f32_32x32x16_f16(Af, B, acc[rt], 0, 0, 0);
        }
      }
      Bc0 = Bn0;
      Bc1 = Bn1;
    }
  }

  // ---- epilogue 2: relu, d-sum -> out[:, 128:256] ----
#pragma unroll
  for (int rt = 0; rt < 4; ++rt) {
    float s = 0.f;
#pragma unroll
    for (int r = 0; r < 16; ++r) {
      float v = acc[rt][r];
      s += v > 0.f ? v : 0.f;
    }
    s += __shfl_down(s, 32);
    if (lane < 32) out[(size_t)(b0 + rt) * 256 + 128 + n0 + lane] = s;
  }
}

extern "C" void kernel_launch(void* const* d_in, const int* in_sizes, int n_in,
                              void* d_out, int out_size, void* d_ws,
                              size_t ws_size, hipStream_t stream) {
  const float* x0 = (const float*)d_in[0];  // [4096,32,32]
  const float* w0 = (const float*)d_in[1];  // [1,1024,128]
  const float* w1 = (const float*)d_in[2];  // [1,4096,128]
  float* out = (float*)d_out;               // [4096,256]
  char* ws = (char*)d_ws;

  half_t* Wp0 = (half_t*)(ws);                  // 64*2048 f16 = 256 KB
  half_t* Wp1 = (half_t*)(ws + 64 * 2048 * 2);  // 256*2048 f16 = 1 MB

  hipLaunchKernelGGL(prep_w_kernel, dim3(320), dim3(256), 0, stream, w0, w1,
                     Wp0, Wp1);
  hipLaunchKernelGGL(cin_fused_kernel, dim3(1024), dim3(256), 0, stream, x0,
                     Wp0, Wp1, out);
}